// Round 4
// baseline (571.492 us; speedup 1.0000x reference)
//
#include <hip/hip_runtime.h>
#include <hip/hip_bf16.h>

typedef short bh8 __attribute__((ext_vector_type(8)));
typedef float f32x4 __attribute__((ext_vector_type(4)));

#define NBLOCKS 512
#define NWAVES_TOTAL (NBLOCKS * 8)

__device__ __forceinline__ short f2bf(float f) {
  __hip_bfloat16 h = __float2bfloat16(f);
  return *reinterpret_cast<short*>(&h);
}
__device__ __forceinline__ float bf2f(short s) {
  return __uint_as_float(((uint)(ushort)s) << 16);
}
// fragment permutation: feature f -> packed pos so one 16B load per (kf,q)
__device__ __forceinline__ int fpos(int f) {
  int kf = (f >> 5) & 3, h = (f >> 4) & 1, q = (f >> 2) & 3, j = f & 3;
  return (kf << 5) | (q << 3) | (h << 2) | j;
}

// ---- kernel 1: per-node Pa = z@W1a + b1, Pb = z@W1b, bf16 frag-permuted ----
__global__ __launch_bounds__(256) void precompute_p(
    const float* __restrict__ z, const float* __restrict__ W1,
    const float* __restrict__ b1, ushort* __restrict__ Pa,
    ushort* __restrict__ Pb, int NN) {
  __shared__ float zs[4][128];
  const int tid = threadIdx.x;
  const int n0 = blockIdx.x * 4;
  for (int i = tid; i < 512; i += 256) {
    int m = i >> 7, ff = i & 127, n = n0 + m;
    zs[m][ff] = (n < NN) ? z[n * 128 + ff] : 0.f;
  }
  __syncthreads();
  const int f = tid & 127;
  const bool isA = tid < 128;
  const float* w = W1 + (isA ? 0 : 128) * 128 + f;
  float a0, a1, a2, a3;
  a0 = a1 = a2 = a3 = isA ? b1[f] : 0.f;
#pragma unroll 16
  for (int k = 0; k < 128; ++k) {
    float wv = w[(size_t)k * 128];
    a0 += zs[0][k] * wv; a1 += zs[1][k] * wv;
    a2 += zs[2][k] * wv; a3 += zs[3][k] * wv;
  }
  ushort* dst = isA ? Pa : Pb;
  int pos = fpos(f);
  float av[4] = {a0, a1, a2, a3};
#pragma unroll
  for (int m = 0; m < 4; ++m)
    if (n0 + m < NN) dst[(size_t)(n0 + m) * 128 + pos] = (ushort)f2bf(av[m]);
}

// ---- kernel 2: pack W2/W3 into frag-linear bf16 ----
__global__ __launch_bounds__(512) void pack_w(
    const float* __restrict__ W2, const float* __restrict__ W3,
    ushort* __restrict__ w2f, ushort* __restrict__ w3f) {
  int idx = blockIdx.x * 512 + threadIdx.x;
  if (idx >= 16384) return;
  int e = idx & 7, l = (idx >> 3) & 63, kb = (idx >> 9) & 3, ob = idx >> 11;
  int q = l >> 4;
  int k = kb * 32 + (e < 4 ? q * 4 + e : 16 + q * 4 + (e - 4));
  int n = ob * 16 + (l & 15);
  w2f[idx] = (ushort)f2bf(W2[k * 128 + n]);
  w3f[idx] = (ushort)f2bf(W3[k * 128 + n]);
}

// ---- kernel 3: histogram of src buckets (8 nodes/bucket) ----
__global__ __launch_bounds__(256) void hist_kernel(
    const int* __restrict__ ei, int* __restrict__ counts, int E) {
  int e = blockIdx.x * 256 + threadIdx.x;
  if (e < E) {
    int s = __builtin_nontemporal_load(ei + e);
    atomicAdd(&counts[s >> 3], 1);
  }
}

// ---- kernel 4: exclusive scan of counts -> cursor (one wave) ----
__global__ __launch_bounds__(64) void scan_kernel(
    const int* __restrict__ counts, int* __restrict__ cursor, int NB) {
  int lane = threadIdx.x;             // 64 lanes, 32 buckets each -> 2048 cap
  int base = lane * 32;
  int local[32];
  int sum = 0;
#pragma unroll
  for (int i = 0; i < 32; ++i) {
    int v = (base + i < NB) ? counts[base + i] : 0;
    local[i] = sum; sum += v;
  }
  int inc = sum;
#pragma unroll
  for (int d = 1; d < 64; d <<= 1) {
    int u = __shfl_up(inc, d, 64);
    if (lane >= d) inc += u;
  }
  int lanebase = inc - sum;           // exclusive across lanes
#pragma unroll
  for (int i = 0; i < 32; ++i)
    if (base + i < NB) cursor[base + i] = lanebase + local[i];
}

// ---- kernel 5: scatter edges into src-bucket order + pre-gather graph ----
__global__ __launch_bounds__(256) void scatter_kernel(
    const int* __restrict__ ei, const float* __restrict__ graph,
    int* __restrict__ cursor, int* __restrict__ srcS, int* __restrict__ dstS,
    int* __restrict__ eidS, float* __restrict__ gvS, int E, int NN) {
  int e = blockIdx.x * 256 + threadIdx.x;
  if (e >= E) return;
  int s = __builtin_nontemporal_load(ei + e);
  int d = __builtin_nontemporal_load(ei + E + e);
  float g = __builtin_nontemporal_load(graph + (size_t)s * NN + d);
  int pos = atomicAdd(&cursor[s >> 3], 1);
  srcS[pos] = s; dstS[pos] = d; eidS[pos] = e; gvS[pos] = g;
}

// ---- kernel 6: main edge MLP ----
struct alignas(16) SMem {
  ushort w2[16384];      // frag-linear: ((ob*4+kf)*64+lane)*8+e
  ushort w3[16384];
  float b2[128], b3[128], w4[128];
  ushort w1gp[128];      // W1[256][:] bf16, frag-permuted
};

__global__ __launch_bounds__(512, 2) void edge_mlp(
    const ushort* __restrict__ Pa, const ushort* __restrict__ Pb,
    const ushort* __restrict__ w2f, const ushort* __restrict__ w3f,
    const int* __restrict__ srcS, const int* __restrict__ dstS,
    const int* __restrict__ eidS, const float* __restrict__ gvS,
    const float* __restrict__ W1, const float* __restrict__ b2,
    const float* __restrict__ b3, const float* __restrict__ W4,
    const float* __restrict__ b4, float* __restrict__ out, int E) {
  __shared__ SMem s;
  const int tid = threadIdx.x;

  {
    const uint4* s2 = (const uint4*)w2f;
    const uint4* s3 = (const uint4*)w3f;
    uint4* d2 = (uint4*)s.w2;
    uint4* d3 = (uint4*)s.w3;
    for (int i = tid; i < 2048; i += 512) { d2[i] = s2[i]; d3[i] = s3[i]; }
    if (tid < 128) {
      s.b2[tid] = b2[tid]; s.b3[tid] = b3[tid]; s.w4[tid] = W4[tid];
      s.w1gp[fpos(tid)] = (ushort)f2bf(W1[256 * 128 + tid]);
    }
  }
  __syncthreads();

  const float b4v = b4[0];
  const int lane = tid & 63;
  const int c = lane & 15;
  const int q = lane >> 4;
  const int wgid = (int)blockIdx.x * 8 + (tid >> 6);
  const int n_tiles = (E + 63) / 64;
  const f32x4 z4 = {0.f, 0.f, 0.f, 0.f};

  bh8 w1gb[4];
#pragma unroll
  for (int kf = 0; kf < 4; ++kf)
    w1gb[kf] = *(const bh8*)&s.w1gp[kf * 32 + q * 8];

  for (int tile = wgid; tile < n_tiles; tile += NWAVES_TOTAL) {
    const int ebase = tile * 64;

    int se[4], de[4];
    float gv[4];
#pragma unroll
    for (int et = 0; et < 4; ++et) {
      int e = ebase + et * 16 + c;
      if (e >= E) e = E - 1;
      se[et] = __builtin_nontemporal_load(srcS + e);
      de[et] = __builtin_nontemporal_load(dstS + e);
      gv[et] = __builtin_nontemporal_load(gvS + e);
    }

    // ---- layer-1 replacement: bp = relu(Pa[src] + Pb[dst] + g*w1g) ----
    bh8 bp[4][4];
#pragma unroll
    for (int et = 0; et < 4; ++et) {
      const ushort* par = Pa + (size_t)se[et] * 128 + q * 8;
      const ushort* pbr = Pb + (size_t)de[et] * 128 + q * 8;
      bh8 pa8[4], pb8[4];
#pragma unroll
      for (int kf = 0; kf < 4; ++kf) {
        pa8[kf] = *(const bh8*)(par + kf * 32);
        pb8[kf] = *(const bh8*)(pbr + kf * 32);
      }
#pragma unroll
      for (int kf = 0; kf < 4; ++kf) {
        bh8 t;
#pragma unroll
        for (int i = 0; i < 8; ++i) {
          float v = bf2f(pa8[kf][i]) + bf2f(pb8[kf][i]);
          v = fmaf(gv[et], bf2f(w1gb[kf][i]), v);
          t[i] = f2bf(fmaxf(v, 0.f));
        }
        bp[et][kf] = t;
      }
    }

    // ---- layer 2 ----
    f32x4 acc[4][8];
#pragma unroll
    for (int et = 0; et < 4; ++et)
#pragma unroll
      for (int ob = 0; ob < 8; ++ob) acc[et][ob] = z4;
#pragma unroll
    for (int kf = 0; kf < 4; ++kf) {
#pragma unroll
      for (int ob = 0; ob < 8; ++ob) {
        bh8 af = *(const bh8*)&s.w2[((ob * 4 + kf) * 64 + lane) * 8];
#pragma unroll
        for (int et = 0; et < 4; ++et)
          acc[et][ob] = __builtin_amdgcn_mfma_f32_16x16x32_bf16(af, bp[et][kf], acc[et][ob], 0, 0, 0);
      }
    }
    // relu + b2 + pack
#pragma unroll
    for (int et = 0; et < 4; ++et) {
#pragma unroll
      for (int kf = 0; kf < 4; ++kf) {
        bh8 t;
#pragma unroll
        for (int half = 0; half < 2; ++half) {
          int ob = kf * 2 + half;
#pragma unroll
          for (int r = 0; r < 4; ++r) {
            int f = ob * 16 + q * 4 + r;
            float v = fmaxf(acc[et][ob][r] + s.b2[f], 0.f);
            t[half * 4 + r] = f2bf(v);
          }
        }
        bp[et][kf] = t;
      }
    }

    // ---- layer 3 ----
#pragma unroll
    for (int et = 0; et < 4; ++et)
#pragma unroll
      for (int ob = 0; ob < 8; ++ob) acc[et][ob] = z4;
#pragma unroll
    for (int kf = 0; kf < 4; ++kf) {
#pragma unroll
      for (int ob = 0; ob < 8; ++ob) {
        bh8 af = *(const bh8*)&s.w3[((ob * 4 + kf) * 64 + lane) * 8];
#pragma unroll
        for (int et = 0; et < 4; ++et)
          acc[et][ob] = __builtin_amdgcn_mfma_f32_16x16x32_bf16(af, bp[et][kf], acc[et][ob], 0, 0, 0);
      }
    }

    // ---- fused relu3 + layer 4 + sigmoid ----
    float psum[4] = {0.f, 0.f, 0.f, 0.f};
#pragma unroll
    for (int et = 0; et < 4; ++et) {
#pragma unroll
      for (int ob = 0; ob < 8; ++ob) {
#pragma unroll
        for (int r = 0; r < 4; ++r) {
          int f = ob * 16 + q * 4 + r;
          float v = fmaxf(acc[et][ob][r] + s.b3[f], 0.f);
          psum[et] += v * s.w4[f];
        }
      }
    }
#pragma unroll
    for (int et = 0; et < 4; ++et) {
      psum[et] += __shfl_xor(psum[et], 16, 64);
      psum[et] += __shfl_xor(psum[et], 32, 64);
    }
    float vsel = (q == 0) ? psum[0] : (q == 1) ? psum[1] : (q == 2) ? psum[2] : psum[3];
    float val = vsel + b4v;
    float sig = 1.0f / (1.0f + __expf(-val));
    int elin = ebase + q * 16 + c;
    if (elin < E) {
      int eid = __builtin_nontemporal_load(eidS + elin);
      out[eid] = sig;
    }
  }
}

extern "C" void kernel_launch(void* const* d_in, const int* in_sizes, int n_in,
                              void* d_out, int out_size, void* d_ws, size_t ws_size,
                              hipStream_t stream) {
  const float* z     = (const float*)d_in[0];
  const float* graph = (const float*)d_in[2];
  const int*   ei    = (const int*)d_in[3];
  const float* W1 = (const float*)d_in[4];
  const float* b1 = (const float*)d_in[5];
  const float* W2 = (const float*)d_in[6];
  const float* b2 = (const float*)d_in[7];
  const float* W3 = (const float*)d_in[8];
  const float* b3 = (const float*)d_in[9];
  const float* W4 = (const float*)d_in[10];
  const float* b4 = (const float*)d_in[11];
  int E  = in_sizes[3] / 2;
  int NN = in_sizes[0] / 128;
  int NB = (NN + 7) >> 3;   // src buckets of 8 nodes

  char* w = (char*)d_ws;
  size_t o = 0;
  auto alloc = [&](size_t bytes) { void* p = w + o; o = (o + bytes + 255) & ~(size_t)255; return p; };
  ushort* Pa     = (ushort*)alloc((size_t)NN * 128 * 2);
  ushort* Pb     = (ushort*)alloc((size_t)NN * 128 * 2);
  ushort* w2f    = (ushort*)alloc(16384 * 2);
  ushort* w3f    = (ushort*)alloc(16384 * 2);
  int*    counts = (int*)alloc((size_t)NB * 4);
  int*    cursor = (int*)alloc((size_t)NB * 4);
  int*    srcS   = (int*)alloc((size_t)E * 4);
  int*    dstS   = (int*)alloc((size_t)E * 4);
  int*    eidS   = (int*)alloc((size_t)E * 4);
  float*  gvS    = (float*)alloc((size_t)E * 4);

  hipMemsetAsync(counts, 0, (size_t)NB * 4, stream);
  hipLaunchKernelGGL(precompute_p, dim3((NN + 3) / 4), dim3(256), 0, stream,
                     z, W1, b1, Pa, Pb, NN);
  hipLaunchKernelGGL(pack_w, dim3(32), dim3(512), 0, stream, W2, W3, w2f, w3f);
  hipLaunchKernelGGL(hist_kernel, dim3((E + 255) / 256), dim3(256), 0, stream,
                     ei, counts, E);
  hipLaunchKernelGGL(scan_kernel, dim3(1), dim3(64), 0, stream, counts, cursor, NB);
  hipLaunchKernelGGL(scatter_kernel, dim3((E + 255) / 256), dim3(256), 0, stream,
                     ei, graph, cursor, srcS, dstS, eidS, gvS, E, NN);
  hipLaunchKernelGGL(edge_mlp, dim3(NBLOCKS), dim3(512), 0, stream,
                     Pa, Pb, w2f, w3f, srcS, dstS, eidS, gvS, W1, b2, b3, W4, b4,
                     (float*)d_out, E);
}

// Round 6
// 314.839 us; speedup vs baseline: 1.8152x; 1.8152x over previous
//
#include <hip/hip_runtime.h>
#include <hip/hip_bf16.h>

typedef short bh8 __attribute__((ext_vector_type(8)));
typedef float f32x4 __attribute__((ext_vector_type(4)));
typedef uint u32x4 __attribute__((ext_vector_type(4)));

#define NBLOCKS_MAIN 512
#define EPB 512            // edges per sort-block

__device__ __forceinline__ short f2bf(float f) {
  __hip_bfloat16 h = __float2bfloat16(f);
  return *reinterpret_cast<short*>(&h);
}
__device__ __forceinline__ float bf2f(short s) {
  return __uint_as_float(((uint)(ushort)s) << 16);
}
__device__ __forceinline__ int fpos(int f) {
  int kf = (f >> 5) & 3, h = (f >> 4) & 1, q = (f >> 2) & 3, j = f & 3;
  return (kf << 5) | (q << 3) | (h << 2) | j;
}

// ---- kernel 1: per-node Pa = z@W1a + b1, Pb = z@W1b, bf16 frag-permuted ----
__global__ __launch_bounds__(256) void precompute_p(
    const float* __restrict__ z, const float* __restrict__ W1,
    const float* __restrict__ b1, ushort* __restrict__ Pa,
    ushort* __restrict__ Pb, int NN) {
  __shared__ float zs[4][128];
  const int tid = threadIdx.x;
  const int n0 = blockIdx.x * 4;
  for (int i = tid; i < 512; i += 256) {
    int m = i >> 7, ff = i & 127, n = n0 + m;
    zs[m][ff] = (n < NN) ? z[n * 128 + ff] : 0.f;
  }
  __syncthreads();
  const int f = tid & 127;
  const bool isA = tid < 128;
  const float* w = W1 + (isA ? 0 : 128) * 128 + f;
  float a0, a1, a2, a3;
  a0 = a1 = a2 = a3 = isA ? b1[f] : 0.f;
#pragma unroll 16
  for (int k = 0; k < 128; ++k) {
    float wv = w[(size_t)k * 128];
    a0 += zs[0][k] * wv; a1 += zs[1][k] * wv;
    a2 += zs[2][k] * wv; a3 += zs[3][k] * wv;
  }
  ushort* dst = isA ? Pa : Pb;
  int pos = fpos(f);
  float av[4] = {a0, a1, a2, a3};
#pragma unroll
  for (int m = 0; m < 4; ++m)
    if (n0 + m < NN) dst[(size_t)(n0 + m) * 128 + pos] = (ushort)f2bf(av[m]);
}

// ---- kernel 2: pack W2/W3 into frag-linear bf16 ----
__global__ __launch_bounds__(512) void pack_w(
    const float* __restrict__ W2, const float* __restrict__ W3,
    ushort* __restrict__ w2f, ushort* __restrict__ w3f) {
  int idx = blockIdx.x * 512 + threadIdx.x;
  if (idx >= 16384) return;
  int e = idx & 7, l = (idx >> 3) & 63, kb = (idx >> 9) & 3, ob = idx >> 11;
  int q = l >> 4;
  int k = kb * 32 + (e < 4 ? q * 4 + e : 16 + q * 4 + (e - 4));
  int n = ob * 16 + (l & 15);
  w2f[idx] = (ushort)f2bf(W2[k * 128 + n]);
  w3f[idx] = (ushort)f2bf(W3[k * 128 + n]);
}

__device__ __forceinline__ int edge_key(int s, int d, int sdiv, int NN) {
  return (s / sdiv) * 2 + ((2 * d >= NN) ? 1 : 0);   // 16 buckets
}

// ---- kernel 3: per-block 16-bucket histogram (LDS atomics only) ----
__global__ __launch_bounds__(256) void hist16(
    const int* __restrict__ ei, int* __restrict__ H, int E, int NN, int NSB) {
  __shared__ int h[16];
  const int tid = threadIdx.x, j = blockIdx.x;
  if (tid < 16) h[tid] = 0;
  __syncthreads();
#pragma unroll
  for (int r = 0; r < EPB / 256; ++r) {
    int e = j * EPB + r * 256 + tid;
    if (e < E) {
      int s = __builtin_nontemporal_load(ei + e);
      int d = __builtin_nontemporal_load(ei + E + e);
      atomicAdd(&h[edge_key(s, d, (NN + 7) / 8, NN)], 1);
    }
  }
  __syncthreads();
  if (tid < 16) H[tid * NSB + j] = h[tid];
}

// ---- kernel 4: scan H (16 waves, one per bucket) -> global slot offsets ----
__global__ __launch_bounds__(1024) void scan16(
    int* __restrict__ H, int* __restrict__ bases, int NSB) {
  const int w = threadIdx.x >> 6, lane = threadIdx.x & 63;
  __shared__ int tot[16];
  __shared__ int bas[17];
  int total = 0;
  for (int bj = 0; bj < NSB; bj += 64) {
    int j = bj + lane;
    total += (j < NSB) ? H[w * NSB + j] : 0;
  }
#pragma unroll
  for (int d = 1; d < 64; d <<= 1) total += __shfl_xor(total, d, 64);
  if (lane == 0) tot[w] = total;
  __syncthreads();
  if (threadIdx.x == 0) {
    int a = 0;
#pragma unroll
    for (int b = 0; b < 16; ++b) { bas[b] = a; a += tot[b]; }
    bas[16] = a;
  }
  __syncthreads();
  int running = bas[w];
  for (int bj = 0; bj < NSB; bj += 64) {
    int j = bj + lane;
    int v = (j < NSB) ? H[w * NSB + j] : 0;
    int inc = v;
#pragma unroll
    for (int d = 1; d < 64; d <<= 1) {
      int u = __shfl_up(inc, d, 64);
      if (lane >= d) inc += u;
    }
    if (j < NSB) H[w * NSB + j] = running + (inc - v);
    running += __shfl(inc, 63, 64);
  }
  if (threadIdx.x < 17) bases[threadIdx.x] = bas[threadIdx.x];
}

// ---- kernel 5: scatter into bucket order + pre-gather graph (no global atomics) ----
__global__ __launch_bounds__(256) void scatter16(
    const int* __restrict__ ei, const float* __restrict__ graph,
    const int* __restrict__ H, u32x4* __restrict__ packed,
    int E, int NN, int NSB) {
  __shared__ int cur[16];
  const int tid = threadIdx.x, j = blockIdx.x;
  if (tid < 16) cur[tid] = H[tid * NSB + j];
  __syncthreads();
#pragma unroll
  for (int r = 0; r < EPB / 256; ++r) {
    int e = j * EPB + r * 256 + tid;
    if (e < E) {
      int s = __builtin_nontemporal_load(ei + e);
      int d = __builtin_nontemporal_load(ei + E + e);
      float g = __builtin_nontemporal_load(graph + (size_t)s * NN + d);
      int pos = atomicAdd(&cur[edge_key(s, d, (NN + 7) / 8, NN)], 1);
      u32x4 pk = {(uint)s, (uint)d, (uint)e, __float_as_uint(g)};
      packed[pos] = pk;
    }
  }
}

// ---- kernel 6: main edge MLP, XCD-partitioned ----
struct alignas(16) SMem {
  ushort w2[16384];      // frag-linear: ((ob*4+kf)*64+lane)*8+e
  ushort w3[16384];
  float b2[128], b3[128], w4[128];
  ushort w1gp[128];
};

__global__ __launch_bounds__(512, 2) void edge_mlp(
    const ushort* __restrict__ Pa, const ushort* __restrict__ Pb,
    const ushort* __restrict__ w2f, const ushort* __restrict__ w3f,
    const u32x4* __restrict__ packed, const int* __restrict__ bases,
    const float* __restrict__ W1, const float* __restrict__ b2,
    const float* __restrict__ b3, const float* __restrict__ W4,
    const float* __restrict__ b4, float* __restrict__ out, int E) {
  __shared__ SMem s;
  const int tid = threadIdx.x;
  {
    const uint4* s2 = (const uint4*)w2f;
    const uint4* s3 = (const uint4*)w3f;
    uint4* d2 = (uint4*)s.w2;
    uint4* d3 = (uint4*)s.w3;
    for (int i = tid; i < 2048; i += 512) { d2[i] = s2[i]; d3[i] = s3[i]; }
    if (tid < 128) {
      s.b2[tid] = b2[tid]; s.b3[tid] = b3[tid]; s.w4[tid] = W4[tid];
      s.w1gp[fpos(tid)] = (ushort)f2bf(W1[256 * 128 + tid]);
    }
  }
  __syncthreads();

  const float b4v = b4[0];
  const int lane = tid & 63;
  const int c = lane & 15;
  const int q = lane >> 4;
  const int xcd = (int)blockIdx.x & 7;             // round-robin dispatch -> XCD
  const int wid = ((int)blockIdx.x >> 3) * 8 + (tid >> 6);   // 0..511 within partition
  const int B0 = bases[2 * xcd];
  const int B1 = bases[2 * xcd + 2];
  const int L = B1 - B0;
  const int tiles = (L + 63) >> 6;
  const int C = (tiles + 511) >> 9;                // contiguous chunk per wave
  const int t0 = wid * C;
  const int t1 = min(t0 + C, tiles);
  const f32x4 z4 = {0.f, 0.f, 0.f, 0.f};

  bh8 w1gb[4];
#pragma unroll
  for (int kf = 0; kf < 4; ++kf)
    w1gb[kf] = *(const bh8*)&s.w1gp[kf * 32 + q * 8];

  for (int t = t0; t < t1; ++t) {
    const int ebase = B0 + t * 64;

    int se[4], de[4], eid[4];
    float gv[4];
#pragma unroll
    for (int et = 0; et < 4; ++et) {
      int e = ebase + et * 16 + c;
      if (e >= B1) e = B1 - 1;
      u32x4 pk = __builtin_nontemporal_load(packed + e);
      se[et] = (int)pk.x; de[et] = (int)pk.y; eid[et] = (int)pk.z;
      gv[et] = __uint_as_float(pk.w);
    }

    // ---- layer-1 replacement: bp = relu(Pa[src] + Pb[dst] + g*w1g) ----
    bh8 bp[4][4];
#pragma unroll
    for (int et = 0; et < 4; ++et) {
      const ushort* par = Pa + (size_t)se[et] * 128 + q * 8;
      const ushort* pbr = Pb + (size_t)de[et] * 128 + q * 8;
      bh8 pa8[4], pb8[4];
#pragma unroll
      for (int kf = 0; kf < 4; ++kf) {
        pa8[kf] = *(const bh8*)(par + kf * 32);
        pb8[kf] = *(const bh8*)(pbr + kf * 32);
      }
#pragma unroll
      for (int kf = 0; kf < 4; ++kf) {
        bh8 t;
#pragma unroll
        for (int i = 0; i < 8; ++i) {
          float v = bf2f(pa8[kf][i]) + bf2f(pb8[kf][i]);
          v = fmaf(gv[et], bf2f(w1gb[kf][i]), v);
          t[i] = f2bf(fmaxf(v, 0.f));
        }
        bp[et][kf] = t;
      }
    }

    // ---- layer 2 ----
    f32x4 acc[4][8];
#pragma unroll
    for (int et = 0; et < 4; ++et)
#pragma unroll
      for (int ob = 0; ob < 8; ++ob) acc[et][ob] = z4;
#pragma unroll
    for (int kf = 0; kf < 4; ++kf) {
#pragma unroll
      for (int ob = 0; ob < 8; ++ob) {
        bh8 af = *(const bh8*)&s.w2[((ob * 4 + kf) * 64 + lane) * 8];
#pragma unroll
        for (int et = 0; et < 4; ++et)
          acc[et][ob] = __builtin_amdgcn_mfma_f32_16x16x32_bf16(af, bp[et][kf], acc[et][ob], 0, 0, 0);
      }
    }
#pragma unroll
    for (int et = 0; et < 4; ++et) {
#pragma unroll
      for (int kf = 0; kf < 4; ++kf) {
        bh8 t;
#pragma unroll
        for (int half = 0; half < 2; ++half) {
          int ob = kf * 2 + half;
#pragma unroll
          for (int r = 0; r < 4; ++r) {
            int f = ob * 16 + q * 4 + r;
            float v = fmaxf(acc[et][ob][r] + s.b2[f], 0.f);
            t[half * 4 + r] = f2bf(v);
          }
        }
        bp[et][kf] = t;
      }
    }

    // ---- layer 3 ----
#pragma unroll
    for (int et = 0; et < 4; ++et)
#pragma unroll
      for (int ob = 0; ob < 8; ++ob) acc[et][ob] = z4;
#pragma unroll
    for (int kf = 0; kf < 4; ++kf) {
#pragma unroll
      for (int ob = 0; ob < 8; ++ob) {
        bh8 af = *(const bh8*)&s.w3[((ob * 4 + kf) * 64 + lane) * 8];
#pragma unroll
        for (int et = 0; et < 4; ++et)
          acc[et][ob] = __builtin_amdgcn_mfma_f32_16x16x32_bf16(af, bp[et][kf], acc[et][ob], 0, 0, 0);
      }
    }

    // ---- fused relu3 + layer 4 + sigmoid ----
    float psum[4] = {0.f, 0.f, 0.f, 0.f};
#pragma unroll
    for (int et = 0; et < 4; ++et) {
#pragma unroll
      for (int ob = 0; ob < 8; ++ob) {
#pragma unroll
        for (int r = 0; r < 4; ++r) {
          int f = ob * 16 + q * 4 + r;
          float v = fmaxf(acc[et][ob][r] + s.b3[f], 0.f);
          psum[et] += v * s.w4[f];
        }
      }
    }
#pragma unroll
    for (int et = 0; et < 4; ++et) {
      psum[et] += __shfl_xor(psum[et], 16, 64);
      psum[et] += __shfl_xor(psum[et], 32, 64);
    }
    float vsel = (q == 0) ? psum[0] : (q == 1) ? psum[1] : (q == 2) ? psum[2] : psum[3];
    int eidsel = (q == 0) ? eid[0] : (q == 1) ? eid[1] : (q == 2) ? eid[2] : eid[3];
    float val = vsel + b4v;
    float sig = 1.0f / (1.0f + __expf(-val));
    int elin = ebase + q * 16 + c;
    if (elin < B1) out[eidsel] = sig;
  }
}

extern "C" void kernel_launch(void* const* d_in, const int* in_sizes, int n_in,
                              void* d_out, int out_size, void* d_ws, size_t ws_size,
                              hipStream_t stream) {
  const float* z     = (const float*)d_in[0];
  const float* graph = (const float*)d_in[2];
  const int*   ei    = (const int*)d_in[3];
  const float* W1 = (const float*)d_in[4];
  const float* b1 = (const float*)d_in[5];
  const float* W2 = (const float*)d_in[6];
  const float* b2 = (const float*)d_in[7];
  const float* W3 = (const float*)d_in[8];
  const float* b3 = (const float*)d_in[9];
  const float* W4 = (const float*)d_in[10];
  const float* b4 = (const float*)d_in[11];
  int E  = in_sizes[3] / 2;
  int NN = in_sizes[0] / 128;
  int NSB = (E + EPB - 1) / EPB;

  char* w = (char*)d_ws;
  size_t o = 0;
  auto alloc = [&](size_t bytes) { void* p = w + o; o = (o + bytes + 255) & ~(size_t)255; return p; };
  ushort* Pa     = (ushort*)alloc((size_t)NN * 128 * 2);
  ushort* Pb     = (ushort*)alloc((size_t)NN * 128 * 2);
  ushort* w2f    = (ushort*)alloc(16384 * 2);
  ushort* w3f    = (ushort*)alloc(16384 * 2);
  int*    H      = (int*)alloc((size_t)16 * NSB * 4);
  int*    bases  = (int*)alloc(32 * 4);
  u32x4*  packed = (u32x4*)alloc((size_t)E * 16);

  hipLaunchKernelGGL(precompute_p, dim3((NN + 3) / 4), dim3(256), 0, stream,
                     z, W1, b1, Pa, Pb, NN);
  hipLaunchKernelGGL(pack_w, dim3(32), dim3(512), 0, stream, W2, W3, w2f, w3f);
  hipLaunchKernelGGL(hist16, dim3(NSB), dim3(256), 0, stream, ei, H, E, NN, NSB);
  hipLaunchKernelGGL(scan16, dim3(1), dim3(1024), 0, stream, H, bases, NSB);
  hipLaunchKernelGGL(scatter16, dim3(NSB), dim3(256), 0, stream,
                     ei, graph, H, packed, E, NN, NSB);
  hipLaunchKernelGGL(edge_mlp, dim3(NBLOCKS_MAIN), dim3(512), 0, stream,
                     Pa, Pb, w2f, w3f, packed, bases, W1, b2, b3, W4, b4,
                     (float*)d_out, E);
}

// Round 7
// 204.802 us; speedup vs baseline: 2.7905x; 1.5373x over previous
//
#include <hip/hip_runtime.h>
#include <hip/hip_bf16.h>

typedef short bh8 __attribute__((ext_vector_type(8)));
typedef float f32x4 __attribute__((ext_vector_type(4)));
typedef uint u32x4 __attribute__((ext_vector_type(4)));

#define NBLOCKS_MAIN 512
#define EPB 512            // edges per sort-block

__device__ __forceinline__ short f2bf(float f) {
  __hip_bfloat16 h = __float2bfloat16(f);
  return *reinterpret_cast<short*>(&h);
}
__device__ __forceinline__ float bf2f(short s) {
  return __uint_as_float(((uint)(ushort)s) << 16);
}
__device__ __forceinline__ int fpos(int f) {
  int kf = (f >> 5) & 3, h = (f >> 4) & 1, q = (f >> 2) & 3, j = f & 3;
  return (kf << 5) | (q << 3) | (h << 2) | j;
}
__device__ __forceinline__ int get_xcd() {
  uint x;
  asm volatile("s_getreg_b32 %0, hwreg(HW_REG_XCC_ID)" : "=s"(x));
  return (int)(x & 7u);
}

// ---- kernel 1: per-node Pa = z@W1a + b1, Pb = z@W1b, bf16 frag-permuted ----
__global__ __launch_bounds__(256) void precompute_p(
    const float* __restrict__ z, const float* __restrict__ W1,
    const float* __restrict__ b1, ushort* __restrict__ Pa,
    ushort* __restrict__ Pb, int NN) {
  __shared__ float zs[4][128];
  const int tid = threadIdx.x;
  const int n0 = blockIdx.x * 4;
  for (int i = tid; i < 512; i += 256) {
    int m = i >> 7, ff = i & 127, n = n0 + m;
    zs[m][ff] = (n < NN) ? z[n * 128 + ff] : 0.f;
  }
  __syncthreads();
  const int f = tid & 127;
  const bool isA = tid < 128;
  const float* w = W1 + (isA ? 0 : 128) * 128 + f;
  float a0, a1, a2, a3;
  a0 = a1 = a2 = a3 = isA ? b1[f] : 0.f;
#pragma unroll 16
  for (int k = 0; k < 128; ++k) {
    float wv = w[(size_t)k * 128];
    a0 += zs[0][k] * wv; a1 += zs[1][k] * wv;
    a2 += zs[2][k] * wv; a3 += zs[3][k] * wv;
  }
  ushort* dst = isA ? Pa : Pb;
  int pos = fpos(f);
  float av[4] = {a0, a1, a2, a3};
#pragma unroll
  for (int m = 0; m < 4; ++m)
    if (n0 + m < NN) dst[(size_t)(n0 + m) * 128 + pos] = (ushort)f2bf(av[m]);
}

// ---- kernel 2: pack W2/W3 into frag-linear bf16 ----
__global__ __launch_bounds__(512) void pack_w(
    const float* __restrict__ W2, const float* __restrict__ W3,
    ushort* __restrict__ w2f, ushort* __restrict__ w3f) {
  int idx = blockIdx.x * 512 + threadIdx.x;
  if (idx >= 16384) return;
  int e = idx & 7, l = (idx >> 3) & 63, kb = (idx >> 9) & 3, ob = idx >> 11;
  int q = l >> 4;
  int k = kb * 32 + (e < 4 ? q * 4 + e : 16 + q * 4 + (e - 4));
  int n = ob * 16 + (l & 15);
  w2f[idx] = (ushort)f2bf(W2[k * 128 + n]);
  w3f[idx] = (ushort)f2bf(W3[k * 128 + n]);
}

__device__ __forceinline__ int edge_key(int s, int d, int sdiv, int NN) {
  return (s / sdiv) * 2 + ((2 * d >= NN) ? 1 : 0);   // 16 buckets
}

// ---- kernel 3: per-block 16-bucket histogram (LDS atomics only) ----
__global__ __launch_bounds__(256) void hist16(
    const int* __restrict__ ei, int* __restrict__ H, int E, int NN, int NSB) {
  __shared__ int h[16];
  const int tid = threadIdx.x, j = blockIdx.x;
  if (tid < 16) h[tid] = 0;
  __syncthreads();
#pragma unroll
  for (int r = 0; r < EPB / 256; ++r) {
    int e = j * EPB + r * 256 + tid;
    if (e < E) {
      int s = __builtin_nontemporal_load(ei + e);
      int d = __builtin_nontemporal_load(ei + E + e);
      atomicAdd(&h[edge_key(s, d, (NN + 7) / 8, NN)], 1);
    }
  }
  __syncthreads();
  if (tid < 16) H[tid * NSB + j] = h[tid];
}

// ---- kernel 4: scan H (16 waves, one per bucket) -> global slot offsets ----
__global__ __launch_bounds__(1024) void scan16(
    int* __restrict__ H, int* __restrict__ bases, int NSB) {
  const int w = threadIdx.x >> 6, lane = threadIdx.x & 63;
  __shared__ int tot[16];
  __shared__ int bas[17];
  int total = 0;
  for (int bj = 0; bj < NSB; bj += 64) {
    int j = bj + lane;
    total += (j < NSB) ? H[w * NSB + j] : 0;
  }
#pragma unroll
  for (int d = 1; d < 64; d <<= 1) total += __shfl_xor(total, d, 64);
  if (lane == 0) tot[w] = total;
  __syncthreads();
  if (threadIdx.x == 0) {
    int a = 0;
#pragma unroll
    for (int b = 0; b < 16; ++b) { bas[b] = a; a += tot[b]; }
    bas[16] = a;
  }
  __syncthreads();
  int running = bas[w];
  for (int bj = 0; bj < NSB; bj += 64) {
    int j = bj + lane;
    int v = (j < NSB) ? H[w * NSB + j] : 0;
    int inc = v;
#pragma unroll
    for (int d = 1; d < 64; d <<= 1) {
      int u = __shfl_up(inc, d, 64);
      if (lane >= d) inc += u;
    }
    if (j < NSB) H[w * NSB + j] = running + (inc - v);
    running += __shfl(inc, 63, 64);
  }
  if (threadIdx.x < 17) bases[threadIdx.x] = bas[threadIdx.x];
}

// ---- kernel 5: scatter into bucket order + pre-gather graph (no global atomics) ----
__global__ __launch_bounds__(256) void scatter16(
    const int* __restrict__ ei, const float* __restrict__ graph,
    const int* __restrict__ H, u32x4* __restrict__ packed,
    int E, int NN, int NSB) {
  __shared__ int cur[16];
  const int tid = threadIdx.x, j = blockIdx.x;
  if (tid < 16) cur[tid] = H[tid * NSB + j];
  __syncthreads();
#pragma unroll
  for (int r = 0; r < EPB / 256; ++r) {
    int e = j * EPB + r * 256 + tid;
    if (e < E) {
      int s = __builtin_nontemporal_load(ei + e);
      int d = __builtin_nontemporal_load(ei + E + e);
      float g = __builtin_nontemporal_load(graph + (size_t)s * NN + d);
      int pos = atomicAdd(&cur[edge_key(s, d, (NN + 7) / 8, NN)], 1);
      u32x4 pk = {(uint)s, (uint)d, (uint)e, __float_as_uint(g)};
      packed[pos] = pk;
    }
  }
}

// ---- kernel 6: main edge MLP, physical-XCD work queues ----
struct alignas(16) SMem {
  ushort w2[16384];      // frag-linear: ((ob*4+kf)*64+lane)*8+e
  ushort w3[16384];
  float b2[128], b3[128], w4[128];
  ushort w1gp[128];
};

__global__ __launch_bounds__(512, 2) void edge_mlp(
    const ushort* __restrict__ Pa, const ushort* __restrict__ Pb,
    const ushort* __restrict__ w2f, const ushort* __restrict__ w3f,
    const u32x4* __restrict__ packed, const int* __restrict__ bases,
    int* __restrict__ queue,
    const float* __restrict__ W1, const float* __restrict__ b2,
    const float* __restrict__ b3, const float* __restrict__ W4,
    const float* __restrict__ b4, float* __restrict__ out, int E) {
  __shared__ SMem s;
  __shared__ int sh_tb;
  const int tid = threadIdx.x;
  {
    const uint4* s2 = (const uint4*)w2f;
    const uint4* s3 = (const uint4*)w3f;
    uint4* d2 = (uint4*)s.w2;
    uint4* d3 = (uint4*)s.w3;
    for (int i = tid; i < 2048; i += 512) { d2[i] = s2[i]; d3[i] = s3[i]; }
    if (tid < 128) {
      s.b2[tid] = b2[tid]; s.b3[tid] = b3[tid]; s.w4[tid] = W4[tid];
      s.w1gp[fpos(tid)] = (ushort)f2bf(W1[256 * 128 + tid]);
    }
  }
  __syncthreads();

  const float b4v = b4[0];
  const int lane = tid & 63;
  const int c = lane & 15;
  const int q = lane >> 4;
  const int xcd = get_xcd();
  const f32x4 z4 = {0.f, 0.f, 0.f, 0.f};

  bh8 w1gb[4];
#pragma unroll
  for (int kf = 0; kf < 4; ++kf)
    w1gb[kf] = *(const bh8*)&s.w1gp[kf * 32 + q * 8];

  // own partition first, then steal (correct regardless of XCC mapping)
  for (int pp = 0; pp < 8; ++pp) {
    const int part = (xcd + pp) & 7;
    const int B0 = bases[2 * part];
    const int B1 = bases[2 * part + 2];
    const int ptiles = (B1 - B0 + 63) >> 6;
    for (;;) {
      if (tid == 0) sh_tb = atomicAdd(&queue[part], 8);
      __syncthreads();
      const int tb = sh_tb;
      __syncthreads();
      if (tb >= ptiles) break;
      const int t = tb + (tid >> 6);
      if (t < ptiles) {
        const int ebase = B0 + t * 64;

        int se[4], de[4], eid[4];
        float gv[4];
#pragma unroll
        for (int et = 0; et < 4; ++et) {
          int e = ebase + et * 16 + c;
          if (e >= B1) e = B1 - 1;
          u32x4 pk = __builtin_nontemporal_load(packed + e);
          se[et] = (int)pk.x; de[et] = (int)pk.y; eid[et] = (int)pk.z;
          gv[et] = __uint_as_float(pk.w);
        }

        // ---- layer-1 replacement: bp = relu(Pa[src] + Pb[dst] + g*w1g) ----
        bh8 bp[4][4];
#pragma unroll
        for (int et = 0; et < 4; ++et) {
          const ushort* par = Pa + (size_t)se[et] * 128 + q * 8;
          const ushort* pbr = Pb + (size_t)de[et] * 128 + q * 8;
          bh8 pa8[4], pb8[4];
#pragma unroll
          for (int kf = 0; kf < 4; ++kf) {
            pa8[kf] = *(const bh8*)(par + kf * 32);
            pb8[kf] = *(const bh8*)(pbr + kf * 32);
          }
#pragma unroll
          for (int kf = 0; kf < 4; ++kf) {
            bh8 t8;
#pragma unroll
            for (int i = 0; i < 8; ++i) {
              float v = bf2f(pa8[kf][i]) + bf2f(pb8[kf][i]);
              v = fmaf(gv[et], bf2f(w1gb[kf][i]), v);
              t8[i] = f2bf(fmaxf(v, 0.f));
            }
            bp[et][kf] = t8;
          }
        }

        // ---- layer 2 ----
        f32x4 acc[4][8];
#pragma unroll
        for (int et = 0; et < 4; ++et)
#pragma unroll
          for (int ob = 0; ob < 8; ++ob) acc[et][ob] = z4;
#pragma unroll
        for (int kf = 0; kf < 4; ++kf) {
#pragma unroll
          for (int ob = 0; ob < 8; ++ob) {
            bh8 af = *(const bh8*)&s.w2[((ob * 4 + kf) * 64 + lane) * 8];
#pragma unroll
            for (int et = 0; et < 4; ++et)
              acc[et][ob] = __builtin_amdgcn_mfma_f32_16x16x32_bf16(af, bp[et][kf], acc[et][ob], 0, 0, 0);
          }
        }
#pragma unroll
        for (int et = 0; et < 4; ++et) {
#pragma unroll
          for (int kf = 0; kf < 4; ++kf) {
            bh8 t8;
#pragma unroll
            for (int half = 0; half < 2; ++half) {
              int ob = kf * 2 + half;
#pragma unroll
              for (int r = 0; r < 4; ++r) {
                int f = ob * 16 + q * 4 + r;
                float v = fmaxf(acc[et][ob][r] + s.b2[f], 0.f);
                t8[half * 4 + r] = f2bf(v);
              }
            }
            bp[et][kf] = t8;
          }
        }

        // ---- layer 3 ----
#pragma unroll
        for (int et = 0; et < 4; ++et)
#pragma unroll
          for (int ob = 0; ob < 8; ++ob) acc[et][ob] = z4;
#pragma unroll
        for (int kf = 0; kf < 4; ++kf) {
#pragma unroll
          for (int ob = 0; ob < 8; ++ob) {
            bh8 af = *(const bh8*)&s.w3[((ob * 4 + kf) * 64 + lane) * 8];
#pragma unroll
            for (int et = 0; et < 4; ++et)
              acc[et][ob] = __builtin_amdgcn_mfma_f32_16x16x32_bf16(af, bp[et][kf], acc[et][ob], 0, 0, 0);
          }
        }

        // ---- fused relu3 + layer 4 + sigmoid ----
        float psum[4] = {0.f, 0.f, 0.f, 0.f};
#pragma unroll
        for (int et = 0; et < 4; ++et) {
#pragma unroll
          for (int ob = 0; ob < 8; ++ob) {
#pragma unroll
            for (int r = 0; r < 4; ++r) {
              int f = ob * 16 + q * 4 + r;
              float v = fmaxf(acc[et][ob][r] + s.b3[f], 0.f);
              psum[et] += v * s.w4[f];
            }
          }
        }
#pragma unroll
        for (int et = 0; et < 4; ++et) {
          psum[et] += __shfl_xor(psum[et], 16, 64);
          psum[et] += __shfl_xor(psum[et], 32, 64);
        }
        float vsel = (q == 0) ? psum[0] : (q == 1) ? psum[1] : (q == 2) ? psum[2] : psum[3];
        int eidsel = (q == 0) ? eid[0] : (q == 1) ? eid[1] : (q == 2) ? eid[2] : eid[3];
        float val = vsel + b4v;
        float sig = 1.0f / (1.0f + __expf(-val));
        int elin = ebase + q * 16 + c;
        if (elin < B1) out[eidsel] = sig;
      }
      __syncthreads();
    }
  }
}

extern "C" void kernel_launch(void* const* d_in, const int* in_sizes, int n_in,
                              void* d_out, int out_size, void* d_ws, size_t ws_size,
                              hipStream_t stream) {
  const float* z     = (const float*)d_in[0];
  const float* graph = (const float*)d_in[2];
  const int*   ei    = (const int*)d_in[3];
  const float* W1 = (const float*)d_in[4];
  const float* b1 = (const float*)d_in[5];
  const float* W2 = (const float*)d_in[6];
  const float* b2 = (const float*)d_in[7];
  const float* W3 = (const float*)d_in[8];
  const float* b3 = (const float*)d_in[9];
  const float* W4 = (const float*)d_in[10];
  const float* b4 = (const float*)d_in[11];
  int E  = in_sizes[3] / 2;
  int NN = in_sizes[0] / 128;
  int NSB = (E + EPB - 1) / EPB;

  char* w = (char*)d_ws;
  size_t o = 0;
  auto alloc = [&](size_t bytes) { void* p = w + o; o = (o + bytes + 255) & ~(size_t)255; return p; };
  ushort* Pa     = (ushort*)alloc((size_t)NN * 128 * 2);
  ushort* Pb     = (ushort*)alloc((size_t)NN * 128 * 2);
  ushort* w2f    = (ushort*)alloc(16384 * 2);
  ushort* w3f    = (ushort*)alloc(16384 * 2);
  int*    H      = (int*)alloc((size_t)16 * NSB * 4);
  int*    bases  = (int*)alloc(32 * 4);
  int*    queue  = (int*)alloc(8 * 4);
  u32x4*  packed = (u32x4*)alloc((size_t)E * 16);

  hipMemsetAsync(queue, 0, 8 * 4, stream);
  hipLaunchKernelGGL(precompute_p, dim3((NN + 3) / 4), dim3(256), 0, stream,
                     z, W1, b1, Pa, Pb, NN);
  hipLaunchKernelGGL(pack_w, dim3(32), dim3(512), 0, stream, W2, W3, w2f, w3f);
  hipLaunchKernelGGL(hist16, dim3(NSB), dim3(256), 0, stream, ei, H, E, NN, NSB);
  hipLaunchKernelGGL(scan16, dim3(1), dim3(1024), 0, stream, H, bases, NSB);
  hipLaunchKernelGGL(scatter16, dim3(NSB), dim3(256), 0, stream,
                     ei, graph, H, packed, E, NN, NSB);
  hipLaunchKernelGGL(edge_mlp, dim3(NBLOCKS_MAIN), dim3(512), 0, stream,
                     Pa, Pb, w2f, w3f, packed, bases, queue, W1, b2, b3, W4, b4,
                     (float*)d_out, E);
}

// Round 8
// 202.607 us; speedup vs baseline: 2.8207x; 1.0108x over previous
//
#include <hip/hip_runtime.h>
#include <hip/hip_bf16.h>

typedef short bh8 __attribute__((ext_vector_type(8)));
typedef float f32x4 __attribute__((ext_vector_type(4)));
typedef uint u32x4 __attribute__((ext_vector_type(4)));

#define NBLOCKS_MAIN 512
#define EPB 512            // edges per sort-block

__device__ __forceinline__ short f2bf(float f) {
  __hip_bfloat16 h = __float2bfloat16(f);
  return *reinterpret_cast<short*>(&h);
}
__device__ __forceinline__ float bf2f(short s) {
  return __uint_as_float(((uint)(ushort)s) << 16);
}
__device__ __forceinline__ int fpos(int f) {
  int kf = (f >> 5) & 3, h = (f >> 4) & 1, q = (f >> 2) & 3, j = f & 3;
  return (kf << 5) | (q << 3) | (h << 2) | j;
}
__device__ __forceinline__ int get_xcd() {
  uint x;
  asm volatile("s_getreg_b32 %0, hwreg(HW_REG_XCC_ID)" : "=s"(x));
  return (int)(x & 7u);
}

// ---- kernel 1: per-node Pa = z@W1a + b1, Pb = z@W1b, bf16 frag-permuted ----
__global__ __launch_bounds__(256) void precompute_p(
    const float* __restrict__ z, const float* __restrict__ W1,
    const float* __restrict__ b1, ushort* __restrict__ Pa,
    ushort* __restrict__ Pb, int NN) {
  __shared__ float zs[4][128];
  const int tid = threadIdx.x;
  const int n0 = blockIdx.x * 4;
  for (int i = tid; i < 512; i += 256) {
    int m = i >> 7, ff = i & 127, n = n0 + m;
    zs[m][ff] = (n < NN) ? z[n * 128 + ff] : 0.f;
  }
  __syncthreads();
  const int f = tid & 127;
  const bool isA = tid < 128;
  const float* w = W1 + (isA ? 0 : 128) * 128 + f;
  float a0, a1, a2, a3;
  a0 = a1 = a2 = a3 = isA ? b1[f] : 0.f;
#pragma unroll 16
  for (int k = 0; k < 128; ++k) {
    float wv = w[(size_t)k * 128];
    a0 += zs[0][k] * wv; a1 += zs[1][k] * wv;
    a2 += zs[2][k] * wv; a3 += zs[3][k] * wv;
  }
  ushort* dst = isA ? Pa : Pb;
  int pos = fpos(f);
  float av[4] = {a0, a1, a2, a3};
#pragma unroll
  for (int m = 0; m < 4; ++m)
    if (n0 + m < NN) dst[(size_t)(n0 + m) * 128 + pos] = (ushort)f2bf(av[m]);
}

// ---- kernel 2: pack W2/W3 into frag-linear bf16 ----
__global__ __launch_bounds__(512) void pack_w(
    const float* __restrict__ W2, const float* __restrict__ W3,
    ushort* __restrict__ w2f, ushort* __restrict__ w3f) {
  int idx = blockIdx.x * 512 + threadIdx.x;
  if (idx >= 16384) return;
  int e = idx & 7, l = (idx >> 3) & 63, kb = (idx >> 9) & 3, ob = idx >> 11;
  int q = l >> 4;
  int k = kb * 32 + (e < 4 ? q * 4 + e : 16 + q * 4 + (e - 4));
  int n = ob * 16 + (l & 15);
  w2f[idx] = (ushort)f2bf(W2[k * 128 + n]);
  w3f[idx] = (ushort)f2bf(W3[k * 128 + n]);
}

__device__ __forceinline__ int edge_key(int s, int d, int sdiv, int NN) {
  return (s / sdiv) * 2 + ((2 * d >= NN) ? 1 : 0);   // 16 buckets
}

// ---- kernel 3: per-block 16-bucket histogram (LDS atomics only) ----
__global__ __launch_bounds__(256) void hist16(
    const int* __restrict__ ei, int* __restrict__ H, int E, int NN, int NSB) {
  __shared__ int h[16];
  const int tid = threadIdx.x, j = blockIdx.x;
  if (tid < 16) h[tid] = 0;
  __syncthreads();
#pragma unroll
  for (int r = 0; r < EPB / 256; ++r) {
    int e = j * EPB + r * 256 + tid;
    if (e < E) {
      int s = __builtin_nontemporal_load(ei + e);
      int d = __builtin_nontemporal_load(ei + E + e);
      atomicAdd(&h[edge_key(s, d, (NN + 7) / 8, NN)], 1);
    }
  }
  __syncthreads();
  if (tid < 16) H[tid * NSB + j] = h[tid];
}

// ---- kernel 4: scan H (16 waves, one per bucket) -> global slot offsets ----
__global__ __launch_bounds__(1024) void scan16(
    int* __restrict__ H, int* __restrict__ bases, int* __restrict__ queue,
    int NSB) {
  const int w = threadIdx.x >> 6, lane = threadIdx.x & 63;
  __shared__ int tot[16];
  __shared__ int bas[17];
  if (threadIdx.x < 8) queue[threadIdx.x] = 0;   // reset work queues each call
  int total = 0;
  for (int bj = 0; bj < NSB; bj += 64) {
    int j = bj + lane;
    total += (j < NSB) ? H[w * NSB + j] : 0;
  }
#pragma unroll
  for (int d = 1; d < 64; d <<= 1) total += __shfl_xor(total, d, 64);
  if (lane == 0) tot[w] = total;
  __syncthreads();
  if (threadIdx.x == 0) {
    int a = 0;
#pragma unroll
    for (int b = 0; b < 16; ++b) { bas[b] = a; a += tot[b]; }
    bas[16] = a;
  }
  __syncthreads();
  int running = bas[w];
  for (int bj = 0; bj < NSB; bj += 64) {
    int j = bj + lane;
    int v = (j < NSB) ? H[w * NSB + j] : 0;
    int inc = v;
#pragma unroll
    for (int d = 1; d < 64; d <<= 1) {
      int u = __shfl_up(inc, d, 64);
      if (lane >= d) inc += u;
    }
    if (j < NSB) H[w * NSB + j] = running + (inc - v);
    running += __shfl(inc, 63, 64);
  }
  if (threadIdx.x < 17) bases[threadIdx.x] = bas[threadIdx.x];
}

// ---- kernel 5: scatter + forward perm + pre-gather graph ----
__global__ __launch_bounds__(256) void scatter16(
    const int* __restrict__ ei, const float* __restrict__ graph,
    const int* __restrict__ H, u32x4* __restrict__ packed,
    int* __restrict__ perm, int E, int NN, int NSB) {
  __shared__ int cur[16];
  const int tid = threadIdx.x, j = blockIdx.x;
  if (tid < 16) cur[tid] = H[tid * NSB + j];
  __syncthreads();
#pragma unroll
  for (int r = 0; r < EPB / 256; ++r) {
    int e = j * EPB + r * 256 + tid;
    if (e < E) {
      int s = __builtin_nontemporal_load(ei + e);
      int d = __builtin_nontemporal_load(ei + E + e);
      float g = __builtin_nontemporal_load(graph + (size_t)s * NN + d);
      int pos = atomicAdd(&cur[edge_key(s, d, (NN + 7) / 8, NN)], 1);
      u32x4 pk = {(uint)s, (uint)d, (uint)e, __float_as_uint(g)};
      packed[pos] = pk;
      perm[e] = pos;          // block-local 2KB region -> cheap
    }
  }
}

// ---- kernel 6: main edge MLP, physical-XCD work queues, sequential writes ----
struct alignas(16) SMem {
  ushort w2[16384];      // frag-linear: ((ob*4+kf)*64+lane)*8+e
  ushort w3[16384];
  float b2[128], b3[128], w4[128];
  ushort w1gp[128];
};

__global__ __launch_bounds__(512, 2) void edge_mlp(
    const ushort* __restrict__ Pa, const ushort* __restrict__ Pb,
    const ushort* __restrict__ w2f, const ushort* __restrict__ w3f,
    const u32x4* __restrict__ packed, const int* __restrict__ bases,
    int* __restrict__ queue,
    const float* __restrict__ W1, const float* __restrict__ b2,
    const float* __restrict__ b3, const float* __restrict__ W4,
    const float* __restrict__ b4, float* __restrict__ val_sorted) {
  __shared__ SMem s;
  __shared__ int sh_tb;
  const int tid = threadIdx.x;
  {
    const uint4* s2 = (const uint4*)w2f;
    const uint4* s3 = (const uint4*)w3f;
    uint4* d2 = (uint4*)s.w2;
    uint4* d3 = (uint4*)s.w3;
    for (int i = tid; i < 2048; i += 512) { d2[i] = s2[i]; d3[i] = s3[i]; }
    if (tid < 128) {
      s.b2[tid] = b2[tid]; s.b3[tid] = b3[tid]; s.w4[tid] = W4[tid];
      s.w1gp[fpos(tid)] = (ushort)f2bf(W1[256 * 128 + tid]);
    }
  }
  __syncthreads();

  const float b4v = b4[0];
  const int lane = tid & 63;
  const int c = lane & 15;
  const int q = lane >> 4;
  const int xcd = get_xcd();
  const f32x4 z4 = {0.f, 0.f, 0.f, 0.f};

  bh8 w1gb[4];
#pragma unroll
  for (int kf = 0; kf < 4; ++kf)
    w1gb[kf] = *(const bh8*)&s.w1gp[kf * 32 + q * 8];

  // own partition first, then steal (correct regardless of XCC mapping)
  for (int pp = 0; pp < 8; ++pp) {
    const int part = (xcd + pp) & 7;
    const int B0 = bases[2 * part];
    const int B1 = bases[2 * part + 2];
    const int ptiles = (B1 - B0 + 63) >> 6;
    for (;;) {
      if (tid == 0) sh_tb = atomicAdd(&queue[part], 8);
      __syncthreads();
      const int tb = sh_tb;
      __syncthreads();
      if (tb >= ptiles) break;
      const int t = tb + (tid >> 6);
      if (t < ptiles) {
        const int ebase = B0 + t * 64;

        int se[4], de[4];
        float gv[4];
#pragma unroll
        for (int et = 0; et < 4; ++et) {
          int e = ebase + et * 16 + c;
          if (e >= B1) e = B1 - 1;
          u32x4 pk = __builtin_nontemporal_load(packed + e);
          se[et] = (int)pk.x; de[et] = (int)pk.y;
          gv[et] = __uint_as_float(pk.w);
        }

        // ---- layer-1 replacement: bp = relu(Pa[src] + Pb[dst] + g*w1g) ----
        bh8 bp[4][4];
#pragma unroll
        for (int et = 0; et < 4; ++et) {
          const ushort* par = Pa + (size_t)se[et] * 128 + q * 8;
          const ushort* pbr = Pb + (size_t)de[et] * 128 + q * 8;
          bh8 pa8[4], pb8[4];
#pragma unroll
          for (int kf = 0; kf < 4; ++kf) {
            pa8[kf] = *(const bh8*)(par + kf * 32);
            pb8[kf] = *(const bh8*)(pbr + kf * 32);
          }
#pragma unroll
          for (int kf = 0; kf < 4; ++kf) {
            bh8 t8;
#pragma unroll
            for (int i = 0; i < 8; ++i) {
              float v = bf2f(pa8[kf][i]) + bf2f(pb8[kf][i]);
              v = fmaf(gv[et], bf2f(w1gb[kf][i]), v);
              t8[i] = f2bf(fmaxf(v, 0.f));
            }
            bp[et][kf] = t8;
          }
        }

        // ---- layer 2 ----
        f32x4 acc[4][8];
#pragma unroll
        for (int et = 0; et < 4; ++et)
#pragma unroll
          for (int ob = 0; ob < 8; ++ob) acc[et][ob] = z4;
#pragma unroll
        for (int kf = 0; kf < 4; ++kf) {
#pragma unroll
          for (int ob = 0; ob < 8; ++ob) {
            bh8 af = *(const bh8*)&s.w2[((ob * 4 + kf) * 64 + lane) * 8];
#pragma unroll
            for (int et = 0; et < 4; ++et)
              acc[et][ob] = __builtin_amdgcn_mfma_f32_16x16x32_bf16(af, bp[et][kf], acc[et][ob], 0, 0, 0);
          }
        }
#pragma unroll
        for (int et = 0; et < 4; ++et) {
#pragma unroll
          for (int kf = 0; kf < 4; ++kf) {
            bh8 t8;
#pragma unroll
            for (int half = 0; half < 2; ++half) {
              int ob = kf * 2 + half;
#pragma unroll
              for (int r = 0; r < 4; ++r) {
                int f = ob * 16 + q * 4 + r;
                float v = fmaxf(acc[et][ob][r] + s.b2[f], 0.f);
                t8[half * 4 + r] = f2bf(v);
              }
            }
            bp[et][kf] = t8;
          }
        }

        // ---- layer 3 ----
#pragma unroll
        for (int et = 0; et < 4; ++et)
#pragma unroll
          for (int ob = 0; ob < 8; ++ob) acc[et][ob] = z4;
#pragma unroll
        for (int kf = 0; kf < 4; ++kf) {
#pragma unroll
          for (int ob = 0; ob < 8; ++ob) {
            bh8 af = *(const bh8*)&s.w3[((ob * 4 + kf) * 64 + lane) * 8];
#pragma unroll
            for (int et = 0; et < 4; ++et)
              acc[et][ob] = __builtin_amdgcn_mfma_f32_16x16x32_bf16(af, bp[et][kf], acc[et][ob], 0, 0, 0);
          }
        }

        // ---- fused relu3 + layer 4 + sigmoid ----
        float psum[4] = {0.f, 0.f, 0.f, 0.f};
#pragma unroll
        for (int et = 0; et < 4; ++et) {
#pragma unroll
          for (int ob = 0; ob < 8; ++ob) {
#pragma unroll
            for (int r = 0; r < 4; ++r) {
              int f = ob * 16 + q * 4 + r;
              float v = fmaxf(acc[et][ob][r] + s.b3[f], 0.f);
              psum[et] += v * s.w4[f];
            }
          }
        }
#pragma unroll
        for (int et = 0; et < 4; ++et) {
          psum[et] += __shfl_xor(psum[et], 16, 64);
          psum[et] += __shfl_xor(psum[et], 32, 64);
        }
        float vsel = (q == 0) ? psum[0] : (q == 1) ? psum[1] : (q == 2) ? psum[2] : psum[3];
        float val = vsel + b4v;
        float sig = 1.0f / (1.0f + __expf(-val));
        int elin = ebase + q * 16 + c;
        if (elin < B1) val_sorted[elin] = sig;   // sequential, coalesced
      }
      __syncthreads();
    }
  }
}

// ---- kernel 7: unsort: out[i] = val_sorted[perm[i]] ----
__global__ __launch_bounds__(256) void unsort_k(
    const int* __restrict__ perm, const float* __restrict__ val_sorted,
    float* __restrict__ out, int E) {
  int i4 = (blockIdx.x * 256 + threadIdx.x) * 4;
  if (i4 + 3 < E) {
    int4 p = *(const int4*)(perm + i4);
    float4 v;
    v.x = val_sorted[p.x]; v.y = val_sorted[p.y];
    v.z = val_sorted[p.z]; v.w = val_sorted[p.w];
    *(float4*)(out + i4) = v;
  } else {
    for (int i = i4; i < E; ++i) out[i] = val_sorted[perm[i]];
  }
}

extern "C" void kernel_launch(void* const* d_in, const int* in_sizes, int n_in,
                              void* d_out, int out_size, void* d_ws, size_t ws_size,
                              hipStream_t stream) {
  const float* z     = (const float*)d_in[0];
  const float* graph = (const float*)d_in[2];
  const int*   ei    = (const int*)d_in[3];
  const float* W1 = (const float*)d_in[4];
  const float* b1 = (const float*)d_in[5];
  const float* W2 = (const float*)d_in[6];
  const float* b2 = (const float*)d_in[7];
  const float* W3 = (const float*)d_in[8];
  const float* b3 = (const float*)d_in[9];
  const float* W4 = (const float*)d_in[10];
  const float* b4 = (const float*)d_in[11];
  int E  = in_sizes[3] / 2;
  int NN = in_sizes[0] / 128;
  int NSB = (E + EPB - 1) / EPB;

  char* w = (char*)d_ws;
  size_t o = 0;
  auto alloc = [&](size_t bytes) { void* p = w + o; o = (o + bytes + 255) & ~(size_t)255; return p; };
  ushort* Pa     = (ushort*)alloc((size_t)NN * 128 * 2);
  ushort* Pb     = (ushort*)alloc((size_t)NN * 128 * 2);
  ushort* w2f    = (ushort*)alloc(16384 * 2);
  ushort* w3f    = (ushort*)alloc(16384 * 2);
  int*    H      = (int*)alloc((size_t)16 * NSB * 4);
  int*    bases  = (int*)alloc(32 * 4);
  int*    queue  = (int*)alloc(8 * 4);
  int*    perm   = (int*)alloc((size_t)E * 4);
  float*  vals   = (float*)alloc((size_t)E * 4);
  u32x4*  packed = (u32x4*)alloc((size_t)E * 16);

  hipLaunchKernelGGL(precompute_p, dim3((NN + 3) / 4), dim3(256), 0, stream,
                     z, W1, b1, Pa, Pb, NN);
  hipLaunchKernelGGL(pack_w, dim3(32), dim3(512), 0, stream, W2, W3, w2f, w3f);
  hipLaunchKernelGGL(hist16, dim3(NSB), dim3(256), 0, stream, ei, H, E, NN, NSB);
  hipLaunchKernelGGL(scan16, dim3(1), dim3(1024), 0, stream, H, bases, queue, NSB);
  hipLaunchKernelGGL(scatter16, dim3(NSB), dim3(256), 0, stream,
                     ei, graph, H, packed, perm, E, NN, NSB);
  hipLaunchKernelGGL(edge_mlp, dim3(NBLOCKS_MAIN), dim3(512), 0, stream,
                     Pa, Pb, w2f, w3f, packed, bases, queue, W1, b2, b3, W4, b4,
                     vals);
  hipLaunchKernelGGL(unsort_k, dim3((E / 4 + 255) / 256), dim3(256), 0, stream,
                     perm, vals, (float*)d_out, E);
}